// Round 10
// baseline (260.000 us; speedup 1.0000x reference)
//
#include <hip/hip_runtime.h>
#include <hip/hip_bf16.h>
#include <stdint.h>

#define SEQ      4096
#define BATCH    2
#define NTOK     (BATCH*SEQ)        // 8192
#define DMODEL   768
#define DINNER   1536
#define NHEADS   24
#define HEADDIM  64
#define DSTATE   16
#define NPAD     3200               // GEMM1 padded N (25*128)
#define EPSV     1e-5f
#define CHUNK    64
#define NCHUNK   (SEQ/CHUNK)        // 64
#define SUB      32
#define LNBLK    2048               // prep_kernel: blocks 0..2047 = layernorm

typedef __bf16 bf16x8 __attribute__((ext_vector_type(8)));
typedef float  floatx4 __attribute__((ext_vector_type(4)));

__device__ __forceinline__ unsigned short f2bf(float f) {
    union { float f; uint32_t u; } v; v.f = f;
    uint32_t u = v.u;
    uint32_t r = (u + 0x7fffu + ((u >> 16) & 1u)) >> 16;
    return (unsigned short)r;
}

__device__ __forceinline__ float bf2f(unsigned short h) {
    union { uint32_t u; float f; } v; v.u = (uint32_t)h << 16;
    return v.f;
}

__device__ __forceinline__ float bfl(uint32_t u) {
    union { uint32_t u; float f; } v; v.u = u << 16; return v.f;
}
__device__ __forceinline__ float bfh(uint32_t u) {
    union { uint32_t u; float f; } v; v.u = u & 0xffff0000u; return v.f;
}

__device__ __forceinline__ float siluf(float x) { return x / (1.f + __expf(-x)); }

__device__ __forceinline__ void async_cp16(const void* g, void* l) {
    __builtin_amdgcn_global_load_lds(
        (const __attribute__((address_space(1))) void*)g,
        (__attribute__((address_space(3))) void*)l,
        16, 0, 0);
}

// ---------------------------------------------------------------------------
// prep: blocks [0, LNBLK) = LayerNorm (one wave per token);
//       blocks [LNBLK, ..) = weight conversion (float4-vectorized).
// gate_norm_w folded into wout16 (diagonal right-mul commutes with GEMM2).
// ---------------------------------------------------------------------------
__global__ __launch_bounds__(256) void prep_kernel(
    const float* __restrict__ x, const float* __restrict__ lnw, const float* __restrict__ lnb,
    unsigned short* __restrict__ u16,
    const float* __restrict__ Win, const float* __restrict__ Wout,
    const float* __restrict__ gw,
    unsigned short* __restrict__ win16, unsigned short* __restrict__ wout16)
{
    if (blockIdx.x < LNBLK) {
        int wave = threadIdx.x >> 6, lane = threadIdx.x & 63;
        int token = blockIdx.x * 4 + wave;
        const float* row = x + (size_t)token * DMODEL;
        float4 v[3];
        float s = 0.f, ss = 0.f;
#pragma unroll
        for (int j = 0; j < 3; ++j) {
            v[j] = *(const float4*)(row + lane*4 + j*256);
            s  += v[j].x + v[j].y + v[j].z + v[j].w;
            ss += v[j].x*v[j].x + v[j].y*v[j].y + v[j].z*v[j].z + v[j].w*v[j].w;
        }
#pragma unroll
        for (int o = 32; o > 0; o >>= 1) { s += __shfl_xor(s, o, 64); ss += __shfl_xor(ss, o, 64); }
        float mean = s * (1.f/768.f);
        float var  = ss * (1.f/768.f) - mean*mean;
        float rstd = rsqrtf(var + EPSV);
        unsigned short* brow = u16 + (size_t)token * DMODEL;
#pragma unroll
        for (int j = 0; j < 3; ++j) {
            int cidx = lane*4 + j*256;
            float4 w4 = *(const float4*)(lnw + cidx);
            float4 b4 = *(const float4*)(lnb + cidx);
            float a0 = (v[j].x - mean)*rstd*w4.x + b4.x;
            float a1 = (v[j].y - mean)*rstd*w4.y + b4.y;
            float a2 = (v[j].z - mean)*rstd*w4.z + b4.z;
            float a3 = (v[j].w - mean)*rstd*w4.w + b4.w;
            ushort4 p; p.x = f2bf(a0); p.y = f2bf(a1); p.z = f2bf(a2); p.w = f2bf(a3);
            *(ushort4*)(brow + cidx) = p;
        }
    } else {
        int e = ((blockIdx.x - LNBLK) * 256 + threadIdx.x) * 4;
        const int n1 = NPAD * DMODEL;
        if (e < n1) {
            int r = e / DMODEL;                 // 768 % 4 == 0: float4 stays in-row
            ushort4 p = {0, 0, 0, 0};
            if (r < 3128) {
                float4 v = *(const float4*)(Win + e);
                p.x = f2bf(v.x); p.y = f2bf(v.y); p.z = f2bf(v.z); p.w = f2bf(v.w);
            }
            *(ushort4*)(win16 + e) = p;
        } else {
            int e2 = e - n1;
            if (e2 < DMODEL * DINNER) {
                int row = e2 / DINNER;
                int col = e2 - row * DINNER;    // %4 == 0
                float4 v = *(const float4*)(Wout + e2);
                float4 w = *(const float4*)(gw + col);
                ushort4 p; p.x = f2bf(v.x*w.x); p.y = f2bf(v.y*w.y);
                           p.z = f2bf(v.z*w.z); p.w = f2bf(v.w*w.w);
                *(ushort4*)(wout16 + e2) = p;
            }
        }
    }
}

// ---------------------------------------------------------------------------
// GEMM1: C = u16 @ win16^T.  Block 128x128, BK=64 (12 iters), wave tile 64x64,
// __launch_bounds__(256,3) -> 3 blocks/CU.  XCD swizzle; 8-way chunk XOR LDS
// swizzle -> 0 bank conflicts.
// Split store: z16 | x16 | bcr(f32 32 cols) | raw24(f32 24 cols).
// [R1: 256x256 8-phase regressed (63.8us) -- K=768 too short, grid quantizes.]
// [R3: dt fusion into this epilogue regressed 51.5->65.5 -- straggler tiles.]
// [R9: (256,4) did NOT raise OccupancyPercent (24-26 either way) and drifted
//  +2us -- HW did not co-schedule a 4th block; reverted to (256,3).]
// ---------------------------------------------------------------------------
__global__ __launch_bounds__(256, 3) void gemm1_kernel(
    const unsigned short* __restrict__ A, const unsigned short* __restrict__ Bt,
    unsigned short* __restrict__ z16, unsigned short* __restrict__ x16,
    float* __restrict__ bcr, float* __restrict__ raw24)
{
    constexpr int K = DMODEL;
    __shared__ unsigned short As[128*64];   // 16 KB
    __shared__ unsigned short Bs[128*64];   // 16 KB
    const int tid  = threadIdx.x;
    const int lane = tid & 63;
    const int wave = tid >> 6;
    const int id   = blockIdx.x;
    const int xcd  = id & 7;
    const int j5   = id >> 3;               // 0..199
    const int m0 = (xcd*8 + (j5 & 7)) * 128;
    const int n0 = (j5 >> 3) * 128;
    const int wm = (wave & 1) * 64;
    const int wn = (wave >> 1) * 64;

    floatx4 acc[4][4];
#pragma unroll
    for (int i = 0; i < 4; ++i)
#pragma unroll
        for (int j = 0; j < 4; ++j) acc[i][j] = floatx4{0.f, 0.f, 0.f, 0.f};

    const int srow8  = lane >> 3;                 // 0..7
    const int schunk = lane & 7;
    const int sscol  = (schunk ^ srow8) * 8;

    for (int k0 = 0; k0 < K; k0 += 64) {
        __syncthreads();
#pragma unroll
        for (int o = 0; o < 4; ++o) {             // A: wave rows [wave*32, +32)
            int row = wave*32 + o*8 + srow8;
            async_cp16(A + (size_t)(m0 + row) * K + k0 + sscol, As + row*64 + schunk*8);
        }
#pragma unroll
        for (int o = 0; o < 4; ++o) {             // B: wave rows [wave*32, +32)
            int row = wave*32 + o*8 + srow8;
            async_cp16(Bt + (size_t)(n0 + row) * K + k0 + sscol, Bs + row*64 + schunk*8);
        }
        __syncthreads();
        const int fr  = lane & 15;
        const int q8  = lane >> 4;
        const int key = fr & 7;
#pragma unroll
        for (int ks = 0; ks < 2; ++ks) {
            const int ch = ((ks*4 + q8) ^ key) * 8;
            bf16x8 a[4], b[4];
#pragma unroll
            for (int i = 0; i < 4; ++i)
                a[i] = *(const bf16x8*)(As + (wm + i*16 + fr)*64 + ch);
#pragma unroll
            for (int j = 0; j < 4; ++j)
                b[j] = *(const bf16x8*)(Bs + (wn + j*16 + fr)*64 + ch);
#pragma unroll
            for (int i = 0; i < 4; ++i)
#pragma unroll
                for (int j = 0; j < 4; ++j)
                    acc[i][j] = __builtin_amdgcn_mfma_f32_16x16x32_bf16(a[i], b[j], acc[i][j], 0, 0, 0);
        }
    }

    const int col = lane & 15;
    const int rq  = (lane >> 4) * 4;
    if (n0 < DINNER) {                      // tiles 0..11 -> z
#pragma unroll
        for (int i = 0; i < 4; ++i)
#pragma unroll
            for (int j = 0; j < 4; ++j)
#pragma unroll
                for (int r = 0; r < 4; ++r) {
                    int gm = m0 + wm + i*16 + rq + r;
                    int gn = n0 + wn + j*16 + col;
                    z16[(size_t)gm * DINNER + gn] = f2bf(acc[i][j][r]);
                }
    } else if (n0 < 3072) {                 // tiles 12..23 -> x (bf16)
#pragma unroll
        for (int i = 0; i < 4; ++i)
#pragma unroll
            for (int j = 0; j < 4; ++j)
#pragma unroll
                for (int r = 0; r < 4; ++r) {
                    int gm = m0 + wm + i*16 + rq + r;
                    int gn = n0 + wn + j*16 + col;
                    x16[(size_t)gm * DINNER + (gn - DINNER)] = f2bf(acc[i][j][r]);
                }
    } else {                                // tile 24: B/C -> bcr, dt -> raw24
#pragma unroll
        for (int i = 0; i < 4; ++i)
#pragma unroll
            for (int j = 0; j < 4; ++j)
#pragma unroll
                for (int r = 0; r < 4; ++r) {
                    int gm = m0 + wm + i*16 + rq + r;
                    int gn = n0 + wn + j*16 + col;
                    if (gn < 3104)
                        bcr[(size_t)gm * 32 + (gn - 3072)] = acc[i][j][r];
                    else if (gn < 3128)
                        raw24[(size_t)gm * NHEADS + (gn - 3104)] = acc[i][j][r];
                }
    }
}

// ---------------------------------------------------------------------------
// GEMM2: out = s_m * (g16 @ wout16g^T) + x.  Block 64x128, BK=128 as two
// 64-wide halves: same loads and MFMA per K-128 but HALF the barrier pairs
// (24 -> 12).  LDS 48KB x 3/CU = 144.  s_m = rsqrt(mean(g^2)+eps) computed
// free from staged As tiles.  [R9: non-gemm1 time -5us confirms this.]
// ---------------------------------------------------------------------------
__global__ __launch_bounds__(256, 3) void gemm2_kernel(
    const unsigned short* __restrict__ A, const unsigned short* __restrict__ Bt,
    float* __restrict__ Cf, const float* __restrict__ resid)
{
    constexpr int K = DINNER;
    __shared__ unsigned short As[2][64*64];     // 16 KB
    __shared__ unsigned short Bs[2][128*64];    // 32 KB
    __shared__ float rowss[64];
    const int tid  = threadIdx.x;
    const int lane = tid & 63;
    const int wave = tid >> 6;
    const int id   = blockIdx.x;
    const int xcd  = id & 7;
    const int j6   = id >> 3;               // 0..95
    const int m0 = (xcd*16 + j6/6) * 64;
    const int n0 = (j6 % 6) * 128;
    const int wm = (wave & 1) * 32;
    const int wn = (wave >> 1) * 64;

    floatx4 acc[2][4];
#pragma unroll
    for (int i = 0; i < 2; ++i)
#pragma unroll
        for (int j = 0; j < 4; ++j) acc[i][j] = floatx4{0.f, 0.f, 0.f, 0.f};

    const int srow8  = lane >> 3;
    const int schunk = lane & 7;
    const int sscol  = (schunk ^ srow8) * 8;

    // ss slots: slot0 = tid -> row tid>>3 (0..31); slot1 -> row +32.
    const int sr0 = tid >> 3;                       // 0..31
    const int scc = ((tid & 7) ^ (sr0 & 7)) * 8;    // (sr0+32)&7 == sr0&7
    float rs0 = 0.f, rs1 = 0.f;

    for (int k0 = 0; k0 < K; k0 += 128) {
        __syncthreads();
#pragma unroll
        for (int hh = 0; hh < 2; ++hh) {
#pragma unroll
            for (int o = 0; o < 2; ++o) {
                int row = wave*16 + o*8 + srow8;
                async_cp16(A + (size_t)(m0 + row) * K + k0 + hh*64 + sscol,
                           &As[hh][row*64 + schunk*8]);
            }
#pragma unroll
            for (int o = 0; o < 4; ++o) {
                int row = wave*32 + o*8 + srow8;
                async_cp16(Bt + (size_t)(n0 + row) * K + k0 + hh*64 + sscol,
                           &Bs[hh][row*64 + schunk*8]);
            }
        }
        __syncthreads();
        const int fr  = lane & 15;
        const int q8  = lane >> 4;
        const int key = fr & 7;
#pragma unroll
        for (int hh = 0; hh < 2; ++hh) {
#pragma unroll
            for (int ks = 0; ks < 2; ++ks) {
                const int ch = ((ks*4 + q8) ^ key) * 8;
                bf16x8 a[2], b[4];
#pragma unroll
                for (int i = 0; i < 2; ++i)
                    a[i] = *(const bf16x8*)(&As[hh][(wm + i*16 + fr)*64 + ch]);
#pragma unroll
                for (int j = 0; j < 4; ++j)
                    b[j] = *(const bf16x8*)(&Bs[hh][(wn + j*16 + fr)*64 + ch]);
#pragma unroll
                for (int i = 0; i < 2; ++i)
#pragma unroll
                    for (int j = 0; j < 4; ++j)
                        acc[i][j] = __builtin_amdgcn_mfma_f32_16x16x32_bf16(a[i], b[j], acc[i][j], 0, 0, 0);
            }
            // row sum-of-squares from the staged As half (zero HBM cost)
            bf16x8 q0 = *(const bf16x8*)(&As[hh][sr0*64 + scc]);
            bf16x8 q1 = *(const bf16x8*)(&As[hh][(sr0 + 32)*64 + scc]);
#pragma unroll
            for (int e = 0; e < 8; ++e) {
                float f0 = (float)q0[e]; rs0 += f0*f0;
                float f1 = (float)q1[e]; rs1 += f1*f1;
            }
        }
    }

    // reduce 8 partials/row (lanes 8k..8k+7), write rowss, then epilogue scale
    rs0 += __shfl_xor(rs0, 1, 64); rs0 += __shfl_xor(rs0, 2, 64); rs0 += __shfl_xor(rs0, 4, 64);
    rs1 += __shfl_xor(rs1, 1, 64); rs1 += __shfl_xor(rs1, 2, 64); rs1 += __shfl_xor(rs1, 4, 64);
    if ((lane & 7) == 0) {
        rowss[wave*8 + (lane >> 3)]      = rs0;
        rowss[wave*8 + 32 + (lane >> 3)] = rs1;
    }
    __syncthreads();

    const int col = lane & 15;
    const int rq  = (lane >> 4) * 4;
#pragma unroll
    for (int i = 0; i < 2; ++i)
#pragma unroll
        for (int r = 0; r < 4; ++r) {
            int lrow = wm + i*16 + rq + r;
            int gm = m0 + lrow;
            float sc = rsqrtf(rowss[lrow] * (1.f/1536.f) + EPSV);
#pragma unroll
            for (int j = 0; j < 4; ++j) {
                int gn = n0 + wn + j*16 + col;
                Cf[(size_t)gm * DMODEL + gn] = acc[i][j][r] * sc + resid[(size_t)gm * DMODEL + gn];
            }
        }
}

// ---------------------------------------------------------------------------
// Pass 1 (R10: STATES ONLY): local scan of h per chunk (h init 0), B-side
// only -- 16-col LDS stage, 4 ds_read_b128/step, 16 FMA/step.  No y, no C
// conv, no y16 write (y is produced in full by pass3 from hstart).  dt/dA
// computed inline from raw24; dtT+dAT written out for pass3.
// ---------------------------------------------------------------------------
__global__ __launch_bounds__(256) void scan_pass1(
    const unsigned short* __restrict__ x16, const float* __restrict__ bcr,
    const float* __restrict__ raw24, const float* __restrict__ dt_bias,
    const float* __restrict__ A_log,
    const float* __restrict__ cw, const float* __restrict__ cb,
    float* __restrict__ hloc, float* __restrict__ pprod,
    float* __restrict__ dAT, float* __restrict__ dtT)
{
    int wave = threadIdx.x >> 6, lane = threadIdx.x & 63;
    int blk = blockIdx.x * 4 + wave;
    int c = blk & (NCHUNK-1), bh = blk >> 6;
    int h = bh % NHEADS, b = bh / NHEADS;
    int row0 = b * SEQ + c * CHUNK;
    int l0 = c * CHUNK;
    int tb = h * NTOK + row0;
    __shared__ float braw[4][35][16];
    __shared__ float bsc[4][32][16];
    __shared__ float av[4][32], dv[4][32];

    const int cx = h*64 + lane;
    float cwx0 = cw[cx*4+0], cwx1 = cw[cx*4+1], cwx2 = cw[cx*4+2], cwx3 = cw[cx*4+3];
    float cbx = cb[cx];
    const int nB = lane & 15;
    float cwb0 = cw[(DINNER+nB)*4+0], cwb1 = cw[(DINNER+nB)*4+1];
    float cwb2 = cw[(DINNER+nB)*4+2], cwb3 = cw[(DINNER+nB)*4+3];
    float cbb = cb[DINNER+nB];
    float dtb = dt_bias[h];
    float Ah  = -__expf(A_log[h]);

    float xm3 = (l0 >= 3) ? bf2f(x16[(size_t)(row0-3)*DINNER + cx]) : 0.f;
    float xm2 = (l0 >= 2) ? bf2f(x16[(size_t)(row0-2)*DINNER + cx]) : 0.f;
    float xm1 = (l0 >= 1) ? bf2f(x16[(size_t)(row0-1)*DINNER + cx]) : 0.f;

    float hst[16];
#pragma unroll
    for (int n = 0; n < 16; ++n) hst[n] = 0.f;
    float aprod = 1.f;

    for (int sc = 0; sc < CHUNK/SUB; ++sc) {
        int rb = row0 + sc * SUB;
        int lb = l0 + sc * SUB;
        __syncthreads();
#pragma unroll
        for (int it = 0; it < 3; ++it) {        // B rows rb-3..rb+31 (35x4 float4)
            int idx = it*64 + lane;
            if (idx < 140) {
                int s = idx >> 2, q = idx & 3;
                float4 val = {0.f,0.f,0.f,0.f};
                if (lb - 3 + s >= 0)
                    val = *(const float4*)(bcr + (size_t)(rb-3+s)*32 + q*4);
                *(float4*)&braw[wave][s][q*4] = val;
            }
        }
        if (lane < 32) {                        // fused dt: softplus + dA
            float raw = raw24[(size_t)(rb + lane)*NHEADS + h] + dtb;
            float dt = (raw > 20.f) ? raw : log1pf(__expf(raw));
            float dA = __expf(dt * Ah);
            av[wave][lane] = dA;
            dv[wave][lane] = dt;
            dAT[(size_t)tb + sc*SUB + lane] = dA;
            dtT[(size_t)tb + sc*SUB + lane] = dt;
        }
        float xr[SUB];
#pragma unroll
        for (int s = 0; s < SUB; ++s)
            xr[s] = bf2f(x16[(size_t)(rb+s)*DINNER + cx]);
        __syncthreads();
#pragma unroll
        for (int it = 0; it < 8; ++it) {        // conv B -> bsc
            int s = it*4 + (lane >> 4);
            float v = cbb + braw[wave][s][nB]*cwb0 + braw[wave][s+1][nB]*cwb1
                          + braw[wave][s+2][nB]*cwb2 + braw[wave][s+3][nB]*cwb3;
            bsc[wave][s][nB] = siluf(v);
        }
        __syncthreads();
#pragma unroll 2
        for (int s = 0; s < SUB; ++s) {
            float a = av[wave][s];
            float xc = siluf(cbx + xm3*cwx0 + xm2*cwx1 + xm1*cwx2 + xr[s]*cwx3);
            xm3 = xm2; xm2 = xm1; xm1 = xr[s];
            float scale = dv[wave][s] * xc;
            const float4* bp4 = (const float4*)&bsc[wave][s][0];
            float4 bv[4];
#pragma unroll
            for (int q = 0; q < 4; ++q) bv[q] = bp4[q];      // 4x ds_read_b128
            const float* bp = (const float*)bv;
#pragma unroll
            for (int n = 0; n < 16; ++n) hst[n] = a*hst[n] + scale*bp[n];
            aprod *= a;
        }
    }
    float* o = hloc + (size_t)blk * 1024 + lane * 16;
#pragma unroll
    for (int n = 0; n < 16; ++n) o[n] = hst[n];
    if (lane == 0) pprod[blk] = aprod;
}

// ---------------------------------------------------------------------------
// Pass 2: chunk-state recombination.  192 blocks x 256 thr; bulk-load all 64
// chunk states into LDS (coalesced float4), 64-step scan in LDS, hstart
// streamed out per step.
// ---------------------------------------------------------------------------
__global__ __launch_bounds__(256) void scan_pass2(
    const float* __restrict__ hloc, const float* __restrict__ pprod, float* __restrict__ hstart)
{
    __shared__ float sm[64*256];            // 64 KB: [chunk][elem-quarter]
    __shared__ float pp[64];
    const int tid = threadIdx.x;
    const int bh  = blockIdx.x >> 2;
    const int q   = blockIdx.x & 3;
    const float* src = hloc + (size_t)bh * 65536 + q * 256;
#pragma unroll
    for (int it = 0; it < 16; ++it) {
        int idx = it*256 + tid;             // 0..4095
        int c   = idx >> 6;                 // 0..63
        int e4  = (idx & 63) * 4;           // 0..252
        *(float4*)&sm[c*256 + e4] = *(const float4*)(src + (size_t)c*1024 + e4);
    }
    if (tid < 64) pp[tid] = pprod[bh*64 + tid];
    __syncthreads();
    float h = 0.f;
    float* dst = hstart + (size_t)bh * 65536 + q * 256 + tid;
#pragma unroll 8
    for (int c = 0; c < 64; ++c) {
        dst[(size_t)c * 1024] = h;
        h = pp[c] * h + sm[c*256 + tid];
    }
}

// ---------------------------------------------------------------------------
// Pass 3 (R10: FULL SCAN + GATE): rerun the scan per chunk starting from
// hstart (h0 from pass2), producing final y directly -- mathematically the
// same recurrence as (local scan + cumdecay correction), just associated
// differently.  g = y * silu(z) written to y16 (bf16, unscaled; RMSNorm
// scale + gate_norm_w applied in gemm2).  Replaces the old y16 round-trip
// (-50 MB) at the cost of re-reading x16 (+25 MB).
// ---------------------------------------------------------------------------
__global__ __launch_bounds__(256) void scan_pass3(
    const unsigned short* __restrict__ x16, const float* __restrict__ bcr,
    const float* __restrict__ dAT, const float* __restrict__ dtT,
    const float* __restrict__ cw, const float* __restrict__ cb, const float* __restrict__ Dp,
    const float* __restrict__ hstart, const unsigned short* __restrict__ z16,
    unsigned short* __restrict__ yout16)
{
    int wave = threadIdx.x >> 6, lane = threadIdx.x & 63;
    int blk = blockIdx.x * 4 + wave;
    int c = blk & (NCHUNK-1), bh = blk >> 6;
    int h = bh % NHEADS, b = bh / NHEADS;
    int row0 = b * SEQ + c * CHUNK;
    int l0 = c * CHUNK;
    int tb = h * NTOK + row0;
    __shared__ float bcraw[4][35][32];
    __shared__ float bcsc[4][32][32];     // conv'd: 0..15 = B, 16..31 = C
    __shared__ float av[4][32], dv[4][32];

    const int cx = h*64 + lane;
    float cwx0 = cw[cx*4+0], cwx1 = cw[cx*4+1], cwx2 = cw[cx*4+2], cwx3 = cw[cx*4+3];
    float cbx = cb[cx];
    const int nBC = lane & 31;
    float cwc0 = cw[(DINNER+nBC)*4+0], cwc1 = cw[(DINNER+nBC)*4+1];
    float cwc2 = cw[(DINNER+nBC)*4+2], cwc3 = cw[(DINNER+nBC)*4+3];
    float cbc = cb[DINNER+nBC];
    float Dh = Dp[h];

    float xm3 = (l0 >= 3) ? bf2f(x16[(size_t)(row0-3)*DINNER + cx]) : 0.f;
    float xm2 = (l0 >= 2) ? bf2f(x16[(size_t)(row0-2)*DINNER + cx]) : 0.f;
    float xm1 = (l0 >= 1) ? bf2f(x16[(size_t)(row0-1)*DINNER + cx]) : 0.f;

    float hst[16];
    const float* hs = hstart + (size_t)blk * 1024 + lane * 16;
#pragma unroll
    for (int n = 0; n < 16; ++n) hst[n] = hs[n];

    for (int sc = 0; sc < CHUNK/SUB; ++sc) {
        int rb = row0 + sc * SUB;
        int lb = l0 + sc * SUB;
        __syncthreads();
#pragma unroll
        for (int it = 0; it < 5; ++it) {        // B+C rows rb-3..rb+31 (35x8 float4)
            int idx = it*64 + lane;
            if (idx < 280) {
                int s = idx >> 3, q = idx & 7;
                float4 val = {0.f,0.f,0.f,0.f};
                if (lb - 3 + s >= 0)
                    val = *(const float4*)(bcr + (size_t)(rb-3+s)*32 + q*4);
                *(float4*)&bcraw[wave][s][q*4] = val;
            }
        }
        if (lane < 32) av[wave][lane] = dAT[(size_t)tb + sc*SUB + lane];
        else           dv[wave][lane-32] = dtT[(size_t)tb + sc*SUB + lane - 32];
        float xr[SUB], zr[SUB];
#pragma unroll
        for (int s = 0; s < SUB; ++s) {
            xr[s] = bf2f(x16[(size_t)(rb+s)*DINNER + cx]);
            zr[s] = bf2f(z16[(size_t)(rb+s)*DINNER + cx]);
        }
        __syncthreads();
#pragma unroll
        for (int it = 0; it < 16; ++it) {       // conv B,C -> bcsc
            int s = it*2 + (lane >> 5);
            float v = cbc + bcraw[wave][s][nBC]*cwc0 + bcraw[wave][s+1][nBC]*cwc1
                          + bcraw[wave][s+2][nBC]*cwc2 + bcraw[wave][s+3][nBC]*cwc3;
            bcsc[wave][s][nBC] = siluf(v);
        }
        __syncthreads();
#pragma unroll 2
        for (int s = 0; s < SUB; ++s) {
            float a = av[wave][s];
            float xc = siluf(cbx + xm3*cwx0 + xm2*cwx1 + xm1*cwx2 + xr[s]*cwx3);
            xm3 = xm2; xm2 = xm1; xm1 = xr[s];
            float scale = dv[wave][s] * xc;
            float y = Dh * xc;
            const float4* bp4 = (const float4*)&bcsc[wave][s][0];
            float4 bv[8];
#pragma unroll
            for (int q = 0; q < 8; ++q) bv[q] = bp4[q];      // 8x ds_read_b128
            const float* bp = (const float*)bv;
#pragma unroll
            for (int n = 0; n < 16; ++n) hst[n] = a*hst[n] + scale*bp[n];
#pragma unroll
            for (int n = 0; n < 16; ++n) y += hst[n] * bp[16+n];
            float g = y * siluf(zr[s]);
            yout16[(size_t)(rb+s)*DINNER + cx] = f2bf(g);
        }
    }
}

// ---------------------------------------------------------------------------
extern "C" void kernel_launch(void* const* d_in, const int* in_sizes, int n_in,
                              void* d_out, int out_size, void* d_ws, size_t ws_size,
                              hipStream_t stream)
{
    const float* x        = (const float*)d_in[0];
    const float* ln_w     = (const float*)d_in[1];
    const float* ln_b     = (const float*)d_in[2];
    const float* W_in     = (const float*)d_in[3];
    const float* conv_w   = (const float*)d_in[4];
    const float* conv_b   = (const float*)d_in[5];
    const float* dt_bias  = (const float*)d_in[6];
    const float* A_log    = (const float*)d_in[7];
    const float* Dp       = (const float*)d_in[8];
    const float* gate_w   = (const float*)d_in[9];
    const float* W_out    = (const float*)d_in[10];
    float* out = (float*)d_out;

    char* ws = (char*)d_ws;
    size_t off = 0;
    auto alloc = [&](size_t bytes) -> void* {
        void* p = ws + off;
        off += (bytes + 255) & ~(size_t)255;
        return p;
    };
    unsigned short* u16    = (unsigned short*)alloc((size_t)NTOK*DMODEL*2);            // 12.58 MB
    unsigned short* win16  = (unsigned short*)alloc((size_t)NPAD*DMODEL*2);            //  4.92 MB
    float*          dAT    = (float*)alloc((size_t)NTOK*NHEADS*4);                     //  0.79 MB
    float*          dtT    = (float*)alloc((size_t)NTOK*NHEADS*4);                     //  0.79 MB
    float*          raw24  = (float*)alloc((size_t)NTOK*NHEADS*4);                     //  0.79 MB
    unsigned short* x16    = (unsigned short*)alloc((size_t)NTOK*DINNER*2);            // 25.17 MB
    float*          bcr    = (float*)alloc((size_t)NTOK*32*4);                         //  1.05 MB
    unsigned short* wout16 = (unsigned short*)alloc((size_t)DMODEL*DINNER*2);          //  2.36 MB
    unsigned short* z16    = (unsigned short*)alloc((size_t)NTOK*DINNER*2);            // 25.17 MB
    unsigned short* y16    = (unsigned short*)alloc((size_t)NTOK*DINNER*2);            // 25.17 MB
    unsigned short* g16    = (unsigned short*)alloc((size_t)NTOK*DINNER*2);            // 25.17 MB (hstart home)
    float*          pprod  = (float*)alloc((size_t)BATCH*NHEADS*NCHUNK*4);             //  0.01 MB
    // aliases (lifetime-checked):
    float* hloc   = (float*)u16;    // 12.58 MB == u16 size; u16 dead after gemm1
    float* hstart = (float*)g16;    // g16 otherwise unused (gemm2 reads y16)
    // high-water ~124 MB

    // prep: 2048 LN blocks + 3552 cvt blocks (3637248 weight elems / 1024)
    prep_kernel<<<LNBLK + (NPAD*DMODEL + DMODEL*DINNER)/1024, 256, 0, stream>>>(
        x, ln_w, ln_b, u16, W_in, W_out, gate_w, win16, wout16);
    gemm1_kernel<<<1600, 256, 0, stream>>>(u16, win16, z16, x16, bcr, raw24);
    scan_pass1<<<BATCH*NHEADS*NCHUNK/4, 256, 0, stream>>>(
        x16, bcr, raw24, dt_bias, A_log, conv_w, conv_b, hloc, pprod, dAT, dtT);
    scan_pass2<<<BATCH*NHEADS*4, 256, 0, stream>>>(hloc, pprod, hstart);
    scan_pass3<<<BATCH*NHEADS*NCHUNK/4, 256, 0, stream>>>(
        x16, bcr, dAT, dtT, conv_w, conv_b, Dp, hstart, z16, y16);
    gemm2_kernel<<<768, 256, 0, stream>>>(y16, wout16, out, x);
}

// Round 11
// 247.184 us; speedup vs baseline: 1.0518x; 1.0518x over previous
//
#include <hip/hip_runtime.h>
#include <hip/hip_bf16.h>
#include <stdint.h>

#define SEQ      4096
#define BATCH    2
#define NTOK     (BATCH*SEQ)        // 8192
#define DMODEL   768
#define DINNER   1536
#define NHEADS   24
#define HEADDIM  64
#define DSTATE   16
#define NPAD     3200               // GEMM1 padded N (25*128)
#define EPSV     1e-5f
#define CHUNK    64
#define NCHUNK   (SEQ/CHUNK)        // 64
#define SUB      32
#define LNBLK    2048               // prep_kernel: blocks 0..2047 = layernorm

typedef __bf16 bf16x8 __attribute__((ext_vector_type(8)));
typedef float  floatx4 __attribute__((ext_vector_type(4)));
typedef float  floatx2 __attribute__((ext_vector_type(2)));

__device__ __forceinline__ unsigned short f2bf(float f) {
    union { float f; uint32_t u; } v; v.f = f;
    uint32_t u = v.u;
    uint32_t r = (u + 0x7fffu + ((u >> 16) & 1u)) >> 16;
    return (unsigned short)r;
}

__device__ __forceinline__ float bf2f(unsigned short h) {
    union { uint32_t u; float f; } v; v.u = (uint32_t)h << 16;
    return v.f;
}

__device__ __forceinline__ float bfl(uint32_t u) {
    union { uint32_t u; float f; } v; v.u = u << 16; return v.f;
}
__device__ __forceinline__ float bfh(uint32_t u) {
    union { uint32_t u; float f; } v; v.u = u & 0xffff0000u; return v.f;
}

__device__ __forceinline__ float siluf(float x) { return x / (1.f + __expf(-x)); }

__device__ __forceinline__ void async_cp16(const void* g, void* l) {
    __builtin_amdgcn_global_load_lds(
        (const __attribute__((address_space(1))) void*)g,
        (__attribute__((address_space(3))) void*)l,
        16, 0, 0);
}

// ---------------------------------------------------------------------------
// prep: blocks [0, LNBLK) = LayerNorm (one wave per token);
//       blocks [LNBLK, ..) = weight conversion (float4-vectorized).
// gate_norm_w folded into wout16 (diagonal right-mul commutes with GEMM2).
// ---------------------------------------------------------------------------
__global__ __launch_bounds__(256) void prep_kernel(
    const float* __restrict__ x, const float* __restrict__ lnw, const float* __restrict__ lnb,
    unsigned short* __restrict__ u16,
    const float* __restrict__ Win, const float* __restrict__ Wout,
    const float* __restrict__ gw,
    unsigned short* __restrict__ win16, unsigned short* __restrict__ wout16)
{
    if (blockIdx.x < LNBLK) {
        int wave = threadIdx.x >> 6, lane = threadIdx.x & 63;
        int token = blockIdx.x * 4 + wave;
        const float* row = x + (size_t)token * DMODEL;
        float4 v[3];
        float s = 0.f, ss = 0.f;
#pragma unroll
        for (int j = 0; j < 3; ++j) {
            v[j] = *(const float4*)(row + lane*4 + j*256);
            s  += v[j].x + v[j].y + v[j].z + v[j].w;
            ss += v[j].x*v[j].x + v[j].y*v[j].y + v[j].z*v[j].z + v[j].w*v[j].w;
        }
#pragma unroll
        for (int o = 32; o > 0; o >>= 1) { s += __shfl_xor(s, o, 64); ss += __shfl_xor(ss, o, 64); }
        float mean = s * (1.f/768.f);
        float var  = ss * (1.f/768.f) - mean*mean;
        float rstd = rsqrtf(var + EPSV);
        unsigned short* brow = u16 + (size_t)token * DMODEL;
#pragma unroll
        for (int j = 0; j < 3; ++j) {
            int cidx = lane*4 + j*256;
            float4 w4 = *(const float4*)(lnw + cidx);
            float4 b4 = *(const float4*)(lnb + cidx);
            float a0 = (v[j].x - mean)*rstd*w4.x + b4.x;
            float a1 = (v[j].y - mean)*rstd*w4.y + b4.y;
            float a2 = (v[j].z - mean)*rstd*w4.z + b4.z;
            float a3 = (v[j].w - mean)*rstd*w4.w + b4.w;
            ushort4 p; p.x = f2bf(a0); p.y = f2bf(a1); p.z = f2bf(a2); p.w = f2bf(a3);
            *(ushort4*)(brow + cidx) = p;
        }
    } else {
        int e = ((blockIdx.x - LNBLK) * 256 + threadIdx.x) * 4;
        const int n1 = NPAD * DMODEL;
        if (e < n1) {
            int r = e / DMODEL;                 // 768 % 4 == 0: float4 stays in-row
            ushort4 p = {0, 0, 0, 0};
            if (r < 3128) {
                float4 v = *(const float4*)(Win + e);
                p.x = f2bf(v.x); p.y = f2bf(v.y); p.z = f2bf(v.z); p.w = f2bf(v.w);
            }
            *(ushort4*)(win16 + e) = p;
        } else {
            int e2 = e - n1;
            if (e2 < DMODEL * DINNER) {
                int row = e2 / DINNER;
                int col = e2 - row * DINNER;    // %4 == 0
                float4 v = *(const float4*)(Wout + e2);
                float4 w = *(const float4*)(gw + col);
                ushort4 p; p.x = f2bf(v.x*w.x); p.y = f2bf(v.y*w.y);
                           p.z = f2bf(v.z*w.z); p.w = f2bf(v.w*w.w);
                *(ushort4*)(wout16 + e2) = p;
            }
        }
    }
}

// ---------------------------------------------------------------------------
// GEMM1: C = u16 @ win16^T.  Block 128x128, BK=64 (12 iters), wave tile 64x64,
// __launch_bounds__(256,3) -> 3 blocks/CU.  XCD swizzle; 8-way chunk XOR LDS
// swizzle -> 0 bank conflicts.
// Split store: z16 | x16 | bcr(f32 32 cols) | raw24(f32 24 cols).
// [R1: 256x256 8-phase regressed -- K=768 too short, grid quantizes.]
// [R3: dt fusion into this epilogue regressed -- straggler tiles.]
// [R9: (256,4) did not raise occupancy; HW didn't co-schedule a 4th block.]
// [R10: scan restructure (states-only p1 / full-scan p3) regressed +11us --
//  scan kernels are VALU-bound (HBM 13%), duplicating state-update compute
//  cost more than the 25MB traffic saved.  Reverted.]
// ---------------------------------------------------------------------------
__global__ __launch_bounds__(256, 3) void gemm1_kernel(
    const unsigned short* __restrict__ A, const unsigned short* __restrict__ Bt,
    unsigned short* __restrict__ z16, unsigned short* __restrict__ x16,
    float* __restrict__ bcr, float* __restrict__ raw24)
{
    constexpr int K = DMODEL;
    __shared__ unsigned short As[128*64];   // 16 KB
    __shared__ unsigned short Bs[128*64];   // 16 KB
    const int tid  = threadIdx.x;
    const int lane = tid & 63;
    const int wave = tid >> 6;
    const int id   = blockIdx.x;
    const int xcd  = id & 7;
    const int j5   = id >> 3;               // 0..199
    const int m0 = (xcd*8 + (j5 & 7)) * 128;
    const int n0 = (j5 >> 3) * 128;
    const int wm = (wave & 1) * 64;
    const int wn = (wave >> 1) * 64;

    floatx4 acc[4][4];
#pragma unroll
    for (int i = 0; i < 4; ++i)
#pragma unroll
        for (int j = 0; j < 4; ++j) acc[i][j] = floatx4{0.f, 0.f, 0.f, 0.f};

    const int srow8  = lane >> 3;                 // 0..7
    const int schunk = lane & 7;
    const int sscol  = (schunk ^ srow8) * 8;

    for (int k0 = 0; k0 < K; k0 += 64) {
        __syncthreads();
#pragma unroll
        for (int o = 0; o < 4; ++o) {             // A: wave rows [wave*32, +32)
            int row = wave*32 + o*8 + srow8;
            async_cp16(A + (size_t)(m0 + row) * K + k0 + sscol, As + row*64 + schunk*8);
        }
#pragma unroll
        for (int o = 0; o < 4; ++o) {             // B: wave rows [wave*32, +32)
            int row = wave*32 + o*8 + srow8;
            async_cp16(Bt + (size_t)(n0 + row) * K + k0 + sscol, Bs + row*64 + schunk*8);
        }
        __syncthreads();
        const int fr  = lane & 15;
        const int q8  = lane >> 4;
        const int key = fr & 7;
#pragma unroll
        for (int ks = 0; ks < 2; ++ks) {
            const int ch = ((ks*4 + q8) ^ key) * 8;
            bf16x8 a[4], b[4];
#pragma unroll
            for (int i = 0; i < 4; ++i)
                a[i] = *(const bf16x8*)(As + (wm + i*16 + fr)*64 + ch);
#pragma unroll
            for (int j = 0; j < 4; ++j)
                b[j] = *(const bf16x8*)(Bs + (wn + j*16 + fr)*64 + ch);
#pragma unroll
            for (int i = 0; i < 4; ++i)
#pragma unroll
                for (int j = 0; j < 4; ++j)
                    acc[i][j] = __builtin_amdgcn_mfma_f32_16x16x32_bf16(a[i], b[j], acc[i][j], 0, 0, 0);
        }
    }

    const int col = lane & 15;
    const int rq  = (lane >> 4) * 4;
    if (n0 < DINNER) {                      // tiles 0..11 -> z
#pragma unroll
        for (int i = 0; i < 4; ++i)
#pragma unroll
            for (int j = 0; j < 4; ++j)
#pragma unroll
                for (int r = 0; r < 4; ++r) {
                    int gm = m0 + wm + i*16 + rq + r;
                    int gn = n0 + wn + j*16 + col;
                    z16[(size_t)gm * DINNER + gn] = f2bf(acc[i][j][r]);
                }
    } else if (n0 < 3072) {                 // tiles 12..23 -> x (bf16)
#pragma unroll
        for (int i = 0; i < 4; ++i)
#pragma unroll
            for (int j = 0; j < 4; ++j)
#pragma unroll
                for (int r = 0; r < 4; ++r) {
                    int gm = m0 + wm + i*16 + rq + r;
                    int gn = n0 + wn + j*16 + col;
                    x16[(size_t)gm * DINNER + (gn - DINNER)] = f2bf(acc[i][j][r]);
                }
    } else {                                // tile 24: B/C -> bcr, dt -> raw24
#pragma unroll
        for (int i = 0; i < 4; ++i)
#pragma unroll
            for (int j = 0; j < 4; ++j)
#pragma unroll
                for (int r = 0; r < 4; ++r) {
                    int gm = m0 + wm + i*16 + rq + r;
                    int gn = n0 + wn + j*16 + col;
                    if (gn < 3104)
                        bcr[(size_t)gm * 32 + (gn - 3072)] = acc[i][j][r];
                    else if (gn < 3128)
                        raw24[(size_t)gm * NHEADS + (gn - 3104)] = acc[i][j][r];
                }
    }
}

// ---------------------------------------------------------------------------
// GEMM2: out = s_m * (g16 @ wout16g^T) + x.  Block 64x128, BK=128 as two
// 64-wide halves: same loads and MFMA per K-128 but HALF the barrier pairs
// (24 -> 12).  LDS 48KB x 3/CU = 144.  s_m = rsqrt(mean(g^2)+eps) computed
// free from staged As tiles.  [R9: non-gemm1 time -5us confirms this.]
// ---------------------------------------------------------------------------
__global__ __launch_bounds__(256, 3) void gemm2_kernel(
    const unsigned short* __restrict__ A, const unsigned short* __restrict__ Bt,
    float* __restrict__ Cf, const float* __restrict__ resid)
{
    constexpr int K = DINNER;
    __shared__ unsigned short As[2][64*64];     // 16 KB
    __shared__ unsigned short Bs[2][128*64];    // 32 KB
    __shared__ float rowss[64];
    const int tid  = threadIdx.x;
    const int lane = tid & 63;
    const int wave = tid >> 6;
    const int id   = blockIdx.x;
    const int xcd  = id & 7;
    const int j6   = id >> 3;               // 0..95
    const int m0 = (xcd*16 + j6/6) * 64;
    const int n0 = (j6 % 6) * 128;
    const int wm = (wave & 1) * 32;
    const int wn = (wave >> 1) * 64;

    floatx4 acc[2][4];
#pragma unroll
    for (int i = 0; i < 2; ++i)
#pragma unroll
        for (int j = 0; j < 4; ++j) acc[i][j] = floatx4{0.f, 0.f, 0.f, 0.f};

    const int srow8  = lane >> 3;
    const int schunk = lane & 7;
    const int sscol  = (schunk ^ srow8) * 8;

    // ss slots: slot0 = tid -> row tid>>3 (0..31); slot1 -> row +32.
    const int sr0 = tid >> 3;                       // 0..31
    const int scc = ((tid & 7) ^ (sr0 & 7)) * 8;    // (sr0+32)&7 == sr0&7
    float rs0 = 0.f, rs1 = 0.f;

    for (int k0 = 0; k0 < K; k0 += 128) {
        __syncthreads();
#pragma unroll
        for (int hh = 0; hh < 2; ++hh) {
#pragma unroll
            for (int o = 0; o < 2; ++o) {
                int row = wave*16 + o*8 + srow8;
                async_cp16(A + (size_t)(m0 + row) * K + k0 + hh*64 + sscol,
                           &As[hh][row*64 + schunk*8]);
            }
#pragma unroll
            for (int o = 0; o < 4; ++o) {
                int row = wave*32 + o*8 + srow8;
                async_cp16(Bt + (size_t)(n0 + row) * K + k0 + hh*64 + sscol,
                           &Bs[hh][row*64 + schunk*8]);
            }
        }
        __syncthreads();
        const int fr  = lane & 15;
        const int q8  = lane >> 4;
        const int key = fr & 7;
#pragma unroll
        for (int hh = 0; hh < 2; ++hh) {
#pragma unroll
            for (int ks = 0; ks < 2; ++ks) {
                const int ch = ((ks*4 + q8) ^ key) * 8;
                bf16x8 a[2], b[4];
#pragma unroll
                for (int i = 0; i < 2; ++i)
                    a[i] = *(const bf16x8*)(&As[hh][(wm + i*16 + fr)*64 + ch]);
#pragma unroll
                for (int j = 0; j < 4; ++j)
                    b[j] = *(const bf16x8*)(&Bs[hh][(wn + j*16 + fr)*64 + ch]);
#pragma unroll
                for (int i = 0; i < 2; ++i)
#pragma unroll
                    for (int j = 0; j < 4; ++j)
                        acc[i][j] = __builtin_amdgcn_mfma_f32_16x16x32_bf16(a[i], b[j], acc[i][j], 0, 0, 0);
            }
            // row sum-of-squares from the staged As half (zero HBM cost)
            bf16x8 q0 = *(const bf16x8*)(&As[hh][sr0*64 + scc]);
            bf16x8 q1 = *(const bf16x8*)(&As[hh][(sr0 + 32)*64 + scc]);
#pragma unroll
            for (int e = 0; e < 8; ++e) {
                float f0 = (float)q0[e]; rs0 += f0*f0;
                float f1 = (float)q1[e]; rs1 += f1*f1;
            }
        }
    }

    // reduce 8 partials/row (lanes 8k..8k+7), write rowss, then epilogue scale
    rs0 += __shfl_xor(rs0, 1, 64); rs0 += __shfl_xor(rs0, 2, 64); rs0 += __shfl_xor(rs0, 4, 64);
    rs1 += __shfl_xor(rs1, 1, 64); rs1 += __shfl_xor(rs1, 2, 64); rs1 += __shfl_xor(rs1, 4, 64);
    if ((lane & 7) == 0) {
        rowss[wave*8 + (lane >> 3)]      = rs0;
        rowss[wave*8 + 32 + (lane >> 3)] = rs1;
    }
    __syncthreads();

    const int col = lane & 15;
    const int rq  = (lane >> 4) * 4;
#pragma unroll
    for (int i = 0; i < 2; ++i)
#pragma unroll
        for (int r = 0; r < 4; ++r) {
            int lrow = wm + i*16 + rq + r;
            int gm = m0 + lrow;
            float sc = rsqrtf(rowss[lrow] * (1.f/1536.f) + EPSV);
#pragma unroll
            for (int j = 0; j < 4; ++j) {
                int gn = n0 + wn + j*16 + col;
                Cf[(size_t)gm * DMODEL + gn] = acc[i][j][r] * sc + resid[(size_t)gm * DMODEL + gn];
            }
        }
}

// ---------------------------------------------------------------------------
// Pass 1 (R9 structure restored): local scan (h init 0) with fused conv+silu,
// 4 chunks per 256-thr block; writes local y to y16.  dt/dA fused from raw24.
// R11: h-update and y-dot expressed as floatx2 packed math to trigger
// v_pk_fma_f32 dual-issue (halves the 32 hot-loop FMAs).
// ---------------------------------------------------------------------------
__global__ __launch_bounds__(256) void scan_pass1(
    const unsigned short* __restrict__ x16, const float* __restrict__ bcr,
    const float* __restrict__ raw24, const float* __restrict__ dt_bias,
    const float* __restrict__ A_log,
    const float* __restrict__ cw, const float* __restrict__ cb, const float* __restrict__ Dp,
    float* __restrict__ hloc, float* __restrict__ pprod,
    unsigned short* __restrict__ ylocal16, float* __restrict__ dAT)
{
    int wave = threadIdx.x >> 6, lane = threadIdx.x & 63;
    int blk = blockIdx.x * 4 + wave;
    int c = blk & (NCHUNK-1), bh = blk >> 6;
    int h = bh % NHEADS, b = bh / NHEADS;
    int row0 = b * SEQ + c * CHUNK;
    int l0 = c * CHUNK;
    int tb = h * NTOK + row0;
    __shared__ float bcraw[4][35][32];
    __shared__ float bcsc[4][32][32];     // conv'd: 0..15 = B, 16..31 = C
    __shared__ float av[4][32], dv[4][32];

    const int cx = h*64 + lane;
    float cwx0 = cw[cx*4+0], cwx1 = cw[cx*4+1], cwx2 = cw[cx*4+2], cwx3 = cw[cx*4+3];
    float cbx = cb[cx];
    const int nBC = lane & 31;
    float cwc0 = cw[(DINNER+nBC)*4+0], cwc1 = cw[(DINNER+nBC)*4+1];
    float cwc2 = cw[(DINNER+nBC)*4+2], cwc3 = cw[(DINNER+nBC)*4+3];
    float cbc = cb[DINNER+nBC];
    float Dh = Dp[h];
    float dtb = dt_bias[h];
    float Ah  = -__expf(A_log[h]);

    float xm3 = (l0 >= 3) ? bf2f(x16[(size_t)(row0-3)*DINNER + cx]) : 0.f;
    float xm2 = (l0 >= 2) ? bf2f(x16[(size_t)(row0-2)*DINNER + cx]) : 0.f;
    float xm1 = (l0 >= 1) ? bf2f(x16[(size_t)(row0-1)*DINNER + cx]) : 0.f;

    floatx2 h2[8];
#pragma unroll
    for (int k = 0; k < 8; ++k) h2[k] = floatx2{0.f, 0.f};
    float aprod = 1.f;

    for (int sc = 0; sc < CHUNK/SUB; ++sc) {
        int rb = row0 + sc * SUB;
        int lb = l0 + sc * SUB;
        __syncthreads();
#pragma unroll
        for (int it = 0; it < 5; ++it) {        // B+C rows rb-3..rb+31 (35x8 float4)
            int idx = it*64 + lane;
            if (idx < 280) {
                int s = idx >> 3, q = idx & 7;
                float4 val = {0.f,0.f,0.f,0.f};
                if (lb - 3 + s >= 0)
                    val = *(const float4*)(bcr + (size_t)(rb-3+s)*32 + q*4);
                *(float4*)&bcraw[wave][s][q*4] = val;
            }
        }
        if (lane < 32) {                        // fused dt: softplus + dA
            float raw = raw24[(size_t)(rb + lane)*NHEADS + h] + dtb;
            float dt = (raw > 20.f) ? raw : log1pf(__expf(raw));
            float dA = __expf(dt * Ah);
            av[wave][lane] = dA;
            dv[wave][lane] = dt;
            dAT[(size_t)tb + sc*SUB + lane] = dA;
        }
        float xr[SUB];
#pragma unroll
        for (int s = 0; s < SUB; ++s)
            xr[s] = bf2f(x16[(size_t)(rb+s)*DINNER + cx]);
        __syncthreads();
#pragma unroll
        for (int it = 0; it < 16; ++it) {       // conv B,C -> bcsc
            int s = it*2 + (lane >> 5);
            float v = cbc + bcraw[wave][s][nBC]*cwc0 + bcraw[wave][s+1][nBC]*cwc1
                          + bcraw[wave][s+2][nBC]*cwc2 + bcraw[wave][s+3][nBC]*cwc3;
            bcsc[wave][s][nBC] = siluf(v);
        }
        __syncthreads();
#pragma unroll 2
        for (int s = 0; s < SUB; ++s) {
            float a = av[wave][s];
            float xc = siluf(cbx + xm3*cwx0 + xm2*cwx1 + xm1*cwx2 + xr[s]*cwx3);
            xm3 = xm2; xm2 = xm1; xm1 = xr[s];
            float scale = dv[wave][s] * xc;
            float4 bv[8];
            const float4* bp4 = (const float4*)&bcsc[wave][s][0];
#pragma unroll
            for (int q = 0; q < 8; ++q) bv[q] = bp4[q];      // 8x ds_read_b128
            const floatx2* bp2 = (const floatx2*)bv;         // [0..7]=B, [8..15]=C
            floatx2 a2 = floatx2{a, a};
            floatx2 s2 = floatx2{scale, scale};
            floatx2 y2 = floatx2{0.f, 0.f};
#pragma unroll
            for (int k = 0; k < 8; ++k) {
                h2[k] = a2*h2[k] + s2*bp2[k];                // v_pk_fma_f32
                y2 += h2[k] * bp2[8+k];                      // v_pk_fma_f32
            }
            float y = Dh * xc + y2[0] + y2[1];
            aprod *= a;
            ylocal16[(size_t)(rb+s)*DINNER + cx] = f2bf(y);
        }
    }
    floatx2* o = (floatx2*)(hloc + (size_t)blk * 1024 + lane * 16);
#pragma unroll
    for (int k = 0; k < 8; ++k) o[k] = h2[k];
    if (lane == 0) pprod[blk] = aprod;
}

// ---------------------------------------------------------------------------
// Pass 2: chunk-state recombination.  192 blocks x 256 thr; bulk-load all 64
// chunk states into LDS (coalesced float4), 64-step scan in LDS, hstart
// streamed out per step.
// ---------------------------------------------------------------------------
__global__ __launch_bounds__(256) void scan_pass2(
    const float* __restrict__ hloc, const float* __restrict__ pprod, float* __restrict__ hstart)
{
    __shared__ float sm[64*256];            // 64 KB: [chunk][elem-quarter]
    __shared__ float pp[64];
    const int tid = threadIdx.x;
    const int bh  = blockIdx.x >> 2;
    const int q   = blockIdx.x & 3;
    const float* src = hloc + (size_t)bh * 65536 + q * 256;
#pragma unroll
    for (int it = 0; it < 16; ++it) {
        int idx = it*256 + tid;             // 0..4095
        int c   = idx >> 6;                 // 0..63
        int e4  = (idx & 63) * 4;           // 0..252
        *(float4*)&sm[c*256 + e4] = *(const float4*)(src + (size_t)c*1024 + e4);
    }
    if (tid < 64) pp[tid] = pprod[bh*64 + tid];
    __syncthreads();
    float h = 0.f;
    float* dst = hstart + (size_t)bh * 65536 + q * 256 + tid;
#pragma unroll 8
    for (int c = 0; c < 64; ++c) {
        dst[(size_t)c * 1024] = h;
        h = pp[c] * h + sm[c*256 + tid];
    }
}

// ---------------------------------------------------------------------------
// Pass 3 + gating (R9 structure restored): y_final = y + cumdecay*(C.h_start);
// g = y_final * silu(z) written in-place (bf16, unscaled).  RMSNorm scale and
// gate_norm_w applied downstream in gemm2.  No shfl/atomic here (R4 lesson).
// R11: C.h0 dot expressed as floatx2 packed math (v_pk_fma_f32).
// ---------------------------------------------------------------------------
__global__ __launch_bounds__(256) void scan_pass3(
    const float* __restrict__ bcr, const float* __restrict__ dAT,
    const float* __restrict__ cw, const float* __restrict__ cb,
    const float* __restrict__ hstart, const unsigned short* __restrict__ z16,
    unsigned short* __restrict__ ylocal16)
{
    int wave = threadIdx.x >> 6, lane = threadIdx.x & 63;
    int blk = blockIdx.x * 4 + wave;
    int c = blk & (NCHUNK-1), bh = blk >> 6;
    int h = bh % NHEADS, b = bh / NHEADS;
    int row0 = b * SEQ + c * CHUNK;
    int l0 = c * CHUNK;
    int tb = h * NTOK + row0;
    __shared__ float craw[4][35][16];
    __shared__ float csc[4][32][16];
    __shared__ float av[4][32];

    const int cx = h*64 + lane;
    const int nC = lane & 15;
    float cwc0 = cw[(DINNER+16+nC)*4+0], cwc1 = cw[(DINNER+16+nC)*4+1];
    float cwc2 = cw[(DINNER+16+nC)*4+2], cwc3 = cw[(DINNER+16+nC)*4+3];
    float cbc = cb[DINNER+16+nC];

    floatx2 h02[8];
    const floatx2* hs2 = (const floatx2*)(hstart + (size_t)blk * 1024 + lane * 16);
#pragma unroll
    for (int k = 0; k < 8; ++k) h02[k] = hs2[k];
    float cd = 1.f;

    for (int sc = 0; sc < CHUNK/SUB; ++sc) {
        int rb = row0 + sc * SUB;
        int lb = l0 + sc * SUB;
        __syncthreads();
#pragma unroll
        for (int it = 0; it < 3; ++it) {        // C rows rb-3..rb+31 (35x4 float4)
            int idx = it*64 + lane;
            if (idx < 140) {
                int s = idx >> 2, q = idx & 3;
                float4 val = {0.f,0.f,0.f,0.f};
                if (lb - 3 + s >= 0)
                    val = *(const float4*)(bcr + (size_t)(rb-3+s)*32 + 16 + q*4);
                *(float4*)&craw[wave][s][q*4] = val;
            }
        }
        if (lane < 32) av[wave][lane] = dAT[(size_t)tb + sc*SUB + lane];
        float yr[SUB], zr[SUB];
#pragma unroll
        for (int s = 0; s < SUB; ++s) {
            yr[s] = bf2f(ylocal16[(size_t)(rb+s)*DINNER + cx]);
            zr[s] = bf2f(z16[(size_t)(rb+s)*DINNER + cx]);
        }
        __syncthreads();
#pragma unroll
        for (int it = 0; it < 8; ++it) {        // conv C -> csc
            int s = it*4 + (lane >> 4);
            float v = cbc + craw[wave][s][nC]*cwc0 + craw[wave][s+1][nC]*cwc1
                          + craw[wave][s+2][nC]*cwc2 + craw[wave][s+3][nC]*cwc3;
            csc[wave][s][nC] = siluf(v);
        }
        __syncthreads();
#pragma unroll 2
        for (int s = 0; s < SUB; ++s) {
            cd *= av[wave][s];
            float4 cv[4];
            const float4* cp4 = (const float4*)&csc[wave][s][0];
#pragma unroll
            for (int q = 0; q < 4; ++q) cv[q] = cp4[q];      // 4x ds_read_b128
            const floatx2* cp2 = (const floatx2*)cv;
            floatx2 c2 = floatx2{0.f, 0.f};
#pragma unroll
            for (int k = 0; k < 8; ++k) c2 += cp2[k] * h02[k];   // v_pk_fma_f32
            float corr = c2[0] + c2[1];
            float g = (yr[s] + cd * corr) * siluf(zr[s]);
            ylocal16[(size_t)(rb+s)*DINNER + cx] = f2bf(g);
        }
    }
}

// ---------------------------------------------------------------------------
extern "C" void kernel_launch(void* const* d_in, const int* in_sizes, int n_in,
                              void* d_out, int out_size, void* d_ws, size_t ws_size,
                              hipStream_t stream)
{
    const float* x        = (const float*)d_in[0];
    const float* ln_w     = (const float*)d_in[1];
    const float* ln_b     = (const float*)d_in[2];
    const float* W_in     = (const float*)d_in[3];
    const float* conv_w   = (const float*)d_in[4];
    const float* conv_b   = (const float*)d_in[5];
    const float* dt_bias  = (const float*)d_in[6];
    const float* A_log    = (const float*)d_in[7];
    const float* Dp       = (const float*)d_in[8];
    const float* gate_w   = (const float*)d_in[9];
    const float* W_out    = (const float*)d_in[10];
    float* out = (float*)d_out;

    char* ws = (char*)d_ws;
    size_t off = 0;
    auto alloc = [&](size_t bytes) -> void* {
        void* p = ws + off;
        off += (bytes + 255) & ~(size_t)255;
        return p;
    };
    unsigned short* u16    = (unsigned short*)alloc((size_t)NTOK*DMODEL*2);            // 12.58 MB
    unsigned short* win16  = (unsigned short*)alloc((size_t)NPAD*DMODEL*2);            //  4.92 MB
    float*          dAT    = (float*)alloc((size_t)NTOK*NHEADS*4);                     //  0.79 MB
    float*          raw24  = (float*)alloc((size_t)NTOK*NHEADS*4);                     //  0.79 MB
    unsigned short* x16    = (unsigned short*)alloc((size_t)NTOK*DINNER*2);            // 25.17 MB
    float*          bcr    = (float*)alloc((size_t)NTOK*32*4);                         //  1.05 MB
    unsigned short* wout16 = (unsigned short*)alloc((size_t)DMODEL*DINNER*2);          //  2.36 MB
    unsigned short* z16    = (unsigned short*)alloc((size_t)NTOK*DINNER*2);            // 25.17 MB
    unsigned short* y16    = (unsigned short*)alloc((size_t)NTOK*DINNER*2);            // 25.17 MB
    unsigned short* g16    = (unsigned short*)alloc((size_t)NTOK*DINNER*2);            // 25.17 MB (hstart home)
    float*          pprod  = (float*)alloc((size_t)BATCH*NHEADS*NCHUNK*4);             //  0.01 MB
    // aliases (lifetime-checked):
    float* hloc   = (float*)u16;    // 12.58 MB == u16 size; u16 dead after gemm1
    float* hstart = (float*)g16;    // g16 otherwise unused (gemm2 reads y16)
    // high-water ~123 MB

    // prep: 2048 LN blocks + 3552 cvt blocks (3637248 weight elems / 1024)
    prep_kernel<<<LNBLK + (NPAD*DMODEL + DMODEL*DINNER)/1024, 256, 0, stream>>>(
        x, ln_w, ln_b, u16, W_in, W_out, gate_w, win16, wout16);
    gemm1_kernel<<<1600, 256, 0, stream>>>(u16, win16, z16, x16, bcr, raw24);
    scan_pass1<<<BATCH*NHEADS*NCHUNK/4, 256, 0, stream>>>(
        x16, bcr, raw24, dt_bias, A_log, conv_w, conv_b, Dp, hloc, pprod, y16, dAT);
    scan_pass2<<<BATCH*NHEADS*4, 256, 0, stream>>>(hloc, pprod, hstart);
    scan_pass3<<<BATCH*NHEADS*NCHUNK/4, 256, 0, stream>>>(bcr, dAT, conv_w, conv_b, hstart, z16, y16);
    gemm2_kernel<<<768, 256, 0, stream>>>(y16, wout16, out, x);
}